// Round 2
// baseline (1790.049 us; speedup 1.0000x reference)
//
#include <hip/hip_runtime.h>
#include <stdint.h>

#define OBS 64
#define ACTD 16
#define DIN 80          // OBS+ACT
#define MIX 16
#define FF 4096         // HID*MIX
#define NB 16384        // batch
#define CHUNK 4096      // rows per pipeline chunk (ws safety)
#define LNEPS 1e-5f

typedef float f32x4 __attribute__((ext_vector_type(4)));
typedef short bf16x8 __attribute__((ext_vector_type(8)));

__device__ __forceinline__ unsigned short f2bf(float f) {
    union { float f; uint32_t u; } v; v.f = f;
    uint32_t u = v.u;
    u += 0x7fff + ((u >> 16) & 1);          // RNE
    return (unsigned short)(u >> 16);
}
__device__ __forceinline__ float bf2f(unsigned short h) {
    union { uint32_t u; float f; } v; v.u = ((uint32_t)h) << 16;
    return v.f;
}

// ---------------------------------------------------------------- W2 -> bf16
__global__ __launch_bounds__(256) void k_conv(const float* __restrict__ W,
                                              unsigned short* __restrict__ O, int n4) {
    int i = blockIdx.x * 256 + threadIdx.x;
    if (i >= n4) return;
    float4 v = ((const float4*)W)[i];
    ushort4 o;
    o.x = f2bf(v.x); o.y = f2bf(v.y); o.z = f2bf(v.z); o.w = f2bf(v.w);
    ((ushort4*)O)[i] = o;
}

// ------------------------------------------------- gating (fp64) + top4 + renorm
__global__ __launch_bounds__(256) void k_gate(const float* __restrict__ x, const float* __restrict__ a,
                                              const float* __restrict__ Wg, const float* __restrict__ bg,
                                              float* __restrict__ scores) {
    __shared__ float wgs[MIX * DIN];
    __shared__ float bgs[MIX];
    int t = threadIdx.x;
    for (int e = t; e < MIX * DIN; e += 256) wgs[e] = Wg[e];
    if (t < MIX) bgs[t] = bg[t];
    __syncthreads();
    int row = blockIdx.x * 256 + t;
    float xa[DIN];
    const float4* xp = (const float4*)(x + (size_t)row * OBS);
#pragma unroll
    for (int i = 0; i < OBS / 4; ++i) {
        float4 v = xp[i];
        xa[i*4] = v.x; xa[i*4+1] = v.y; xa[i*4+2] = v.z; xa[i*4+3] = v.w;
    }
    const float4* ap = (const float4*)(a + (size_t)row * ACTD);
#pragma unroll
    for (int i = 0; i < ACTD / 4; ++i) {
        float4 v = ap[i];
        xa[OBS+i*4] = v.x; xa[OBS+i*4+1] = v.y; xa[OBS+i*4+2] = v.z; xa[OBS+i*4+3] = v.w;
    }
    double p[MIX];
    double mx = -1e300;
#pragma unroll
    for (int m = 0; m < MIX; ++m) {
        double acc = (double)bgs[m];
#pragma unroll
        for (int k = 0; k < DIN; ++k) acc += (double)xa[k] * (double)wgs[m*DIN + k];
        p[m] = acc;
        if (acc > mx) mx = acc;
    }
#pragma unroll
    for (int m = 0; m < MIX; ++m) p[m] = exp(p[m] - mx);
    // top-4 (strict >, earliest index on ties), renormalize over selected
    unsigned used = 0;
    double s4 = 0.0;
#pragma unroll
    for (int j = 0; j < 4; ++j) {
        int best = 0; double bv = -1.0;
#pragma unroll
        for (int m = 0; m < MIX; ++m)
            if (!((used >> m) & 1) && p[m] > bv) { bv = p[m]; best = m; }
        used |= 1u << best;
        s4 += bv;
    }
    float* so = scores + (size_t)row * MIX;
#pragma unroll
    for (int m = 0; m < MIX; ++m)
        so[m] = ((used >> m) & 1) ? (float)(p[m] / s4) : 0.f;
}

// ---------------------------- fused GEMM1 (fp32 VALU) + b1 + LN1 + ReLU -> h1 (bf16)
// block: 256 threads, 32 rows; thread tile 2 rows x 4 cols over 64-col chunks
#define R1 32
__global__ __launch_bounds__(256) void k_mlp1(const float* __restrict__ x, const float* __restrict__ a,
                                              const float* __restrict__ W1, const float* __restrict__ b1,
                                              const float* __restrict__ g1, const float* __restrict__ be1,
                                              unsigned short* __restrict__ h1) {
    __shared__ float xs[DIN * 36];   // xa transposed [k][r], pad 36
    __shared__ float wt[DIN * 68];   // W1 chunk transposed [k][c], pad 68
    int t = threadIdx.x;
    int r0 = blockIdx.x * R1;
    int ci = t & 15, ri = t >> 4;

    for (int e = t; e < R1 * OBS; e += 256) {
        int r = e >> 6, c = e & 63;
        xs[c * 36 + r] = x[(size_t)(r0 + r) * OBS + c];
    }
    for (int e = t; e < R1 * ACTD; e += 256) {
        int r = e >> 4, c = e & 15;
        xs[(OBS + c) * 36 + r] = a[(size_t)(r0 + r) * ACTD + c];
    }

    float sum0 = 0.f, sum1 = 0.f, sq0 = 0.f, sq1 = 0.f;
    for (int jc = 0; jc < FF; jc += 64) {
        __syncthreads();
        for (int e = t; e < 64 * DIN; e += 256) {
            int c = e / DIN, k = e - c * DIN;
            wt[k * 68 + c] = W1[(size_t)(jc + c) * DIN + k];
        }
        __syncthreads();
        float acc00=0.f,acc01=0.f,acc02=0.f,acc03=0.f;
        float acc10=0.f,acc11=0.f,acc12=0.f,acc13=0.f;
#pragma unroll 8
        for (int k = 0; k < DIN; ++k) {
            float2 av = *(const float2*)(xs + k * 36 + ri * 2);
            f32x4 wv = *(const f32x4*)(wt + k * 68 + ci * 4);
            acc00 += av.x * wv[0]; acc01 += av.x * wv[1]; acc02 += av.x * wv[2]; acc03 += av.x * wv[3];
            acc10 += av.y * wv[0]; acc11 += av.y * wv[1]; acc12 += av.y * wv[2]; acc13 += av.y * wv[3];
        }
        float4 bv = *(const float4*)(b1 + jc + ci * 4);
        float y00 = acc00 + bv.x, y01 = acc01 + bv.y, y02 = acc02 + bv.z, y03 = acc03 + bv.w;
        float y10 = acc10 + bv.x, y11 = acc11 + bv.y, y12 = acc12 + bv.z, y13 = acc13 + bv.w;
        sum0 += y00 + y01 + y02 + y03;
        sq0  += y00*y00 + y01*y01 + y02*y02 + y03*y03;
        sum1 += y10 + y11 + y12 + y13;
        sq1  += y10*y10 + y11*y11 + y12*y12 + y13*y13;
        ushort4 o0, o1;
        o0.x = f2bf(y00); o0.y = f2bf(y01); o0.z = f2bf(y02); o0.w = f2bf(y03);
        o1.x = f2bf(y10); o1.y = f2bf(y11); o1.z = f2bf(y12); o1.w = f2bf(y13);
        *(ushort4*)(h1 + (size_t)(r0 + ri*2 + 0) * FF + jc + ci*4) = o0;
        *(ushort4*)(h1 + (size_t)(r0 + ri*2 + 1) * FF + jc + ci*4) = o1;
    }

    __syncthreads();
    float* sred = xs;                 // [R1][17]
    float* qred = xs + R1 * 17;       // [R1][17]
    float* mus  = qred + R1 * 17;     // [R1]
    float* rss  = mus + R1;           // [R1]
    sred[(ri*2 + 0) * 17 + ci] = sum0;
    sred[(ri*2 + 1) * 17 + ci] = sum1;
    qred[(ri*2 + 0) * 17 + ci] = sq0;
    qred[(ri*2 + 1) * 17 + ci] = sq1;
    __syncthreads();
    if (t < R1) {
        float s = 0.f, q = 0.f;
        for (int i2 = 0; i2 < 16; ++i2) { s += sred[t*17 + i2]; q += qred[t*17 + i2]; }
        float mu = s / (float)FF;
        float var = q / (float)FF - mu * mu;
        mus[t] = mu;
        rss[t] = rsqrtf(var + LNEPS);
    }
    __syncthreads();

    // pass 2: normalize in place (h1 currently holds pre-LN bf16)
    for (int r = 0; r < R1; ++r) {
        float mu = mus[r], rs = rss[r];
        for (int it = 0; it < 2; ++it) {
            int c = (t + it * 256) * 8;
            unsigned short* hp = h1 + (size_t)(r0 + r) * FF + c;
            uint4 u = *(const uint4*)hp;
            float vv[8];
            vv[0] = bf2f((unsigned short)(u.x & 0xffff)); vv[1] = bf2f((unsigned short)(u.x >> 16));
            vv[2] = bf2f((unsigned short)(u.y & 0xffff)); vv[3] = bf2f((unsigned short)(u.y >> 16));
            vv[4] = bf2f((unsigned short)(u.z & 0xffff)); vv[5] = bf2f((unsigned short)(u.z >> 16));
            vv[6] = bf2f((unsigned short)(u.w & 0xffff)); vv[7] = bf2f((unsigned short)(u.w >> 16));
            float4 gg0 = *(const float4*)(g1 + c);
            float4 gg1 = *(const float4*)(g1 + c + 4);
            float4 bb0 = *(const float4*)(be1 + c);
            float4 bb1 = *(const float4*)(be1 + c + 4);
            float gq[8] = {gg0.x, gg0.y, gg0.z, gg0.w, gg1.x, gg1.y, gg1.z, gg1.w};
            float bq[8] = {bb0.x, bb0.y, bb0.z, bb0.w, bb1.x, bb1.y, bb1.z, bb1.w};
            uint32_t w0 = 0, w1 = 0, w2 = 0, w3 = 0;
#pragma unroll
            for (int j = 0; j < 8; ++j) {
                float o = (vv[j] - mu) * rs * gq[j] + bq[j];
                o = fmaxf(o, 0.f);
                uint32_t h = (uint32_t)f2bf(o);
                if (j < 2)      w0 |= h << (16 * (j & 1));
                else if (j < 4) w1 |= h << (16 * (j & 1));
                else if (j < 6) w2 |= h << (16 * (j & 1));
                else            w3 |= h << (16 * (j & 1));
            }
            uint4 ou; ou.x = w0; ou.y = w1; ou.z = w2; ou.w = w3;
            *(uint4*)hp = ou;
        }
    }
}

// ---------------------------------------- GEMM2: y2 = h1 @ W2^T  (bf16 MFMA, m97-style)
// A: [CHUNK, K] bf16 row-major; B: [N, K] bf16 row-major; C: [CHUNK, N] bf16
__global__ __launch_bounds__(256) void k_gemm2(const unsigned short* __restrict__ A,
                                               const unsigned short* __restrict__ B,
                                               unsigned short* __restrict__ C) {
    constexpr int N = FF, K = FF;
    constexpr int BM = 128, BN = 128, BK = 64;
    __shared__ alignas(16) unsigned short As[BM * BK];
    __shared__ alignas(16) unsigned short Bs[BN * BK];
    int t = threadIdx.x;
    int bid = blockIdx.x;
    constexpr int numBN = N / BN;   // 32
    constexpr int GM = 8;
    constexpr int npg = GM * numBN; // 256
    int group = bid / npg;
    int idx = bid - group * npg;
    int pm = group * GM + (idx & 7);
    int pn = idx >> 3;
    int lane = t & 63;
    int wid = t >> 6;
    int wm = wid >> 1, wn = wid & 1;
    int srow = t >> 3, sslot = t & 7;

    const unsigned short* Ap = A + (size_t)pm * BM * K;
    const unsigned short* Bp = B + (size_t)pn * BN * K;

    f32x4 acc[4][4] = {};

    for (int k0 = 0; k0 < K; k0 += BK) {
#pragma unroll
        for (int i = 0; i < 4; ++i) {
            int row = i * 32 + srow;
            int gs = sslot ^ (row & 7);   // pre-swizzled source, linear LDS dest
            __builtin_amdgcn_global_load_lds(
                (const __attribute__((address_space(1))) void*)(Ap + (size_t)row * K + k0 + gs * 8),
                (__attribute__((address_space(3))) void*)(As + i * 2048 + t * 8), 16, 0, 0);
        }
#pragma unroll
        for (int i = 0; i < 4; ++i) {
            int row = i * 32 + srow;
            int gs = sslot ^ (row & 7);
            __builtin_amdgcn_global_load_lds(
                (const __attribute__((address_space(1))) void*)(Bp + (size_t)row * K + k0 + gs * 8),
                (__attribute__((address_space(3))) void*)(Bs + i * 2048 + t * 8), 16, 0, 0);
        }
        __syncthreads();
#pragma unroll
        for (int ks = 0; ks < 2; ++ks) {
            bf16x8 af[4], bfr[4];
#pragma unroll
            for (int mf = 0; mf < 4; ++mf) {
                int r = wm * 64 + mf * 16 + (lane & 15);
                int sl = (ks * 4 + (lane >> 4)) ^ (r & 7);   // swizzled read
                af[mf] = *(const bf16x8*)(As + r * 64 + sl * 8);
            }
#pragma unroll
            for (int nf = 0; nf < 4; ++nf) {
                int r = wn * 64 + nf * 16 + (lane & 15);
                int sl = (ks * 4 + (lane >> 4)) ^ (r & 7);
                bfr[nf] = *(const bf16x8*)(Bs + r * 64 + sl * 8);
            }
#pragma unroll
            for (int mf = 0; mf < 4; ++mf)
#pragma unroll
                for (int nf = 0; nf < 4; ++nf)
                    acc[mf][nf] = __builtin_amdgcn_mfma_f32_16x16x32_bf16(af[mf], bfr[nf], acc[mf][nf], 0, 0, 0);
        }
        __syncthreads();
    }

    int row0 = pm * BM + wm * 64 + (lane >> 4) * 4;
    int col0 = pn * BN + wn * 64 + (lane & 15);
#pragma unroll
    for (int mf = 0; mf < 4; ++mf)
#pragma unroll
        for (int nf = 0; nf < 4; ++nf)
#pragma unroll
            for (int rr = 0; rr < 4; ++rr)
                C[(size_t)(row0 + mf * 16 + rr) * N + col0 + nf * 16] = f2bf(acc[mf][nf][rr]);
}

// ------------------- fused +b2, LN2, ReLU, score mixture, x W3 + b3 -> out[row]
__global__ __launch_bounds__(256) void k_epi(const unsigned short* __restrict__ y2,
                                             const float* __restrict__ scores,
                                             const float* __restrict__ b2,
                                             const float* __restrict__ g2, const float* __restrict__ be2,
                                             const float* __restrict__ W3, const float* __restrict__ b3,
                                             float* __restrict__ out) {
    int row = blockIdx.x, t = threadIdx.x;
    int lane = t & 63, wid = t >> 6;
    __shared__ float sS[MIX];
    __shared__ float rA[4], rB[4];
    __shared__ float stats[2];
    const unsigned short* yp = y2 + (size_t)row * FF + t * 16;
    uint4 u0 = *(const uint4*)yp;
    uint4 u1 = *(const uint4*)(yp + 8);
    float v[16];
    v[0]  = bf2f((unsigned short)(u0.x & 0xffff)); v[1]  = bf2f((unsigned short)(u0.x >> 16));
    v[2]  = bf2f((unsigned short)(u0.y & 0xffff)); v[3]  = bf2f((unsigned short)(u0.y >> 16));
    v[4]  = bf2f((unsigned short)(u0.z & 0xffff)); v[5]  = bf2f((unsigned short)(u0.z >> 16));
    v[6]  = bf2f((unsigned short)(u0.w & 0xffff)); v[7]  = bf2f((unsigned short)(u0.w >> 16));
    v[8]  = bf2f((unsigned short)(u1.x & 0xffff)); v[9]  = bf2f((unsigned short)(u1.x >> 16));
    v[10] = bf2f((unsigned short)(u1.y & 0xffff)); v[11] = bf2f((unsigned short)(u1.y >> 16));
    v[12] = bf2f((unsigned short)(u1.z & 0xffff)); v[13] = bf2f((unsigned short)(u1.z >> 16));
    v[14] = bf2f((unsigned short)(u1.w & 0xffff)); v[15] = bf2f((unsigned short)(u1.w >> 16));
    const float* b2p = b2 + t * 16;
#pragma unroll
    for (int blk = 0; blk < 4; ++blk) {
        float4 q = *(const float4*)(b2p + blk * 4);
        v[blk*4+0] += q.x; v[blk*4+1] += q.y; v[blk*4+2] += q.z; v[blk*4+3] += q.w;
    }
    if (t < MIX) sS[t] = scores[(size_t)row * MIX + t];
    float s = 0.f, sq = 0.f;
#pragma unroll
    for (int j = 0; j < 16; ++j) { s += v[j]; sq += v[j] * v[j]; }
#pragma unroll
    for (int off = 32; off >= 1; off >>= 1) {
        s  += __shfl_down(s, off);
        sq += __shfl_down(sq, off);
    }
    if (lane == 0) { rA[wid] = s; rB[wid] = sq; }
    __syncthreads();
    if (t == 0) {
        float S = rA[0] + rA[1] + rA[2] + rA[3];
        float Q = rB[0] + rB[1] + rB[2] + rB[3];
        float mu = S / (float)FF;
        float var = Q / (float)FF - mu * mu;
        stats[0] = mu;
        stats[1] = rsqrtf(var + LNEPS);
    }
    __syncthreads();
    float mu = stats[0], rs = stats[1];
    const float* gp = g2 + t * 16;
    const float* bp = be2 + t * 16;
    float accum = 0.f;
#pragma unroll
    for (int blk = 0; blk < 4; ++blk) {
        float4 gg = *(const float4*)(gp + blk * 4);
        float4 bb = *(const float4*)(bp + blk * 4);
        float ga[4] = {gg.x, gg.y, gg.z, gg.w};
        float ba[4] = {bb.x, bb.y, bb.z, bb.w};
#pragma unroll
        for (int jj = 0; jj < 4; ++jj) {
            int m = blk * 4 + jj;
            float o = (v[m] - mu) * rs * ga[jj] + ba[jj];
            o = fmaxf(o, 0.f);
            accum += o * sS[m];
        }
    }
    float part = accum * W3[t] * 0.0625f;   // /16 (mean over MIX)
#pragma unroll
    for (int off = 32; off >= 1; off >>= 1) part += __shfl_down(part, off);
    if (lane == 0) rA[wid] = part;
    __syncthreads();
    if (t == 0) out[row] = rA[0] + rA[1] + rA[2] + rA[3] + b3[0];
}

extern "C" void kernel_launch(void* const* d_in, const int* in_sizes, int n_in,
                              void* d_out, int out_size, void* d_ws, size_t ws_size,
                              hipStream_t stream) {
    const float* x   = (const float*)d_in[0];
    const float* a   = (const float*)d_in[1];
    const float* W1  = (const float*)d_in[2];
    const float* b1  = (const float*)d_in[3];
    const float* W2  = (const float*)d_in[4];
    const float* b2  = (const float*)d_in[5];
    const float* W3  = (const float*)d_in[6];
    const float* b3  = (const float*)d_in[7];
    const float* g1  = (const float*)d_in[8];
    const float* be1 = (const float*)d_in[9];
    const float* g2  = (const float*)d_in[10];
    const float* be2 = (const float*)d_in[11];
    const float* Wg  = (const float*)d_in[12];
    const float* bg  = (const float*)d_in[13];
    float* out = (float*)d_out;

    // workspace layout (97 MB total; chunked pipeline keeps it small)
    char* ws = (char*)d_ws;
    unsigned short* W2b   = (unsigned short*)ws;                     // 32 MB
    float*          scores = (float*)(ws + 33554432ull);             // 1 MB
    unsigned short* h1c   = (unsigned short*)(ws + 34603008ull);     // 32 MB
    unsigned short* y2c   = (unsigned short*)(ws + 68157440ull);     // 32 MB

    k_conv<<<(FF * FF / 4 + 255) / 256, 256, 0, stream>>>(W2, W2b, FF * FF / 4);
    k_gate<<<NB / 256, 256, 0, stream>>>(x, a, Wg, bg, scores);

    for (int c = 0; c < NB / CHUNK; ++c) {
        const float* xc = x + (size_t)c * CHUNK * OBS;
        const float* ac = a + (size_t)c * CHUNK * ACTD;
        const float* sc = scores + (size_t)c * CHUNK * MIX;
        float* oc = out + (size_t)c * CHUNK;
        k_mlp1<<<CHUNK / R1, 256, 0, stream>>>(xc, ac, W1, b1, g1, be1, h1c);
        k_gemm2<<<(CHUNK / 128) * (FF / 128), 256, 0, stream>>>(h1c, W2b, y2c);
        k_epi<<<CHUNK, 256, 0, stream>>>(y2c, sc, b2, g2, be2, W3, b3, oc);
    }
}